// Round 1
// baseline (6577.229 us; speedup 1.0000x reference)
//
#include <hip/hip_runtime.h>
#include <hip/hip_bf16.h>

// Inputs/outputs are FLOAT32 (per reference). Compute uses bf16 MFMA.
typedef __attribute__((ext_vector_type(8))) short short8;   // 8 bf16 = 4 VGPRs (MFMA A/B frag)
typedef __attribute__((ext_vector_type(4))) float floatx4;  // MFMA C/D frag

#define TBH ((size_t)16777216)  // 32768*512 per-gate G stride (elements)

__device__ __forceinline__ float bfbits2f(unsigned short b) {
  return __uint_as_float(((unsigned int)b) << 16);
}
__device__ __forceinline__ unsigned short f2bf(float f) {
  unsigned int u = __float_as_uint(f);
  unsigned int r = (u + 0x7fffu + ((u >> 16) & 1u)) >> 16;  // RNE
  return (unsigned short)r;
}

// Relaxed device-scope atomics (bypass non-coherent per-XCD caches). No
// acquire/release anywhere: every exchanged 4B word is self-contained
// (bf16 value in high 16 bits | step tag in low 16 bits), so per-word
// atomicity is the only ordering requirement.
__device__ __forceinline__ void dev_store(unsigned int* p, unsigned int v) {
  __hip_atomic_store(p, v, __ATOMIC_RELAXED, __HIP_MEMORY_SCOPE_AGENT);
}
__device__ __forceinline__ unsigned int dev_load(const unsigned int* p) {
  return __hip_atomic_load(p, __ATOMIC_RELAXED, __HIP_MEMORY_SCOPE_AGENT);
}

// -------------------------------------------------------------------------
// prep: hpub[i] = bf16(h0)|tag0 ; rhpub/ipub = tag0 ; Whr/Whi/Whn -> bf16.
// -------------------------------------------------------------------------
__global__ void prep_kernel(const float* __restrict__ h0,
                            unsigned int* __restrict__ hpub,
                            unsigned int* __restrict__ rhpub,
                            unsigned int* __restrict__ ipub,
                            const float* __restrict__ Whr,
                            const float* __restrict__ Whi,
                            const float* __restrict__ Whn,
                            unsigned short* __restrict__ Whb) {
  int i = blockIdx.x * 256 + threadIdx.x;  // grid 1024*256 = 262144
  if (i < 64 * 512) {
    hpub[i] = ((unsigned int)f2bf(h0[i])) << 16;  // tag 0 == expected at t=0
    rhpub[i] = 0u;                                // tag 0 != 1 (first rh tag)
    ipub[i] = 0u;
  }
#pragma unroll
  for (int rep = 0; rep < 3; ++rep) {
    int j = i + rep * 262144;
    float v = (j < 262144) ? Whr[j] : ((j < 524288) ? Whi[j - 262144] : Whn[j - 524288]);
    Whb[j] = f2bf(v);
  }
}

// -------------------------------------------------------------------------
// Phase 1: G[gate][t*64+b][n] = x@Wi^T + ctx@Wp^T + (bi+bh+bp)   (bf16 out)
// (unchanged from previous round)
// -------------------------------------------------------------------------
struct PreArgs {
  const float* x;
  const float* ctx;
  const float* Wi[3];
  const float* Wp[3];
  const float* bi[3];
  const float* bh[3];
  const float* bp[3];
  unsigned short* G;
};

__global__ __launch_bounds__(256) void gemm_pre(PreArgs args) {
  __shared__ short8 a_sm[512];  // [row(128)][sub(4)] : 128x32 bf16
  __shared__ short8 b_sm[512];
  const int tid = threadIdx.x;
  const int gate = blockIdx.z;
  const int n0 = blockIdx.x * 128;
  const int m0 = blockIdx.y * 128;
  const int wave = tid >> 6, lane = tid & 63;
  const int wm = (wave & 1) * 64, wn = (wave >> 1) * 64;
  const int lm = lane & 15, lq = lane >> 4;
  const float* Wi = args.Wi[gate];
  const float* Wp = args.Wp[gate];

  floatx4 acc[4][4];
#pragma unroll
  for (int i = 0; i < 4; ++i)
#pragma unroll
    for (int j = 0; j < 4; ++j) acc[i][j] = floatx4{0.f, 0.f, 0.f, 0.f};

  for (int kb = 0; kb < 32; ++kb) {
    const float* asrc = (kb < 16) ? args.x : args.ctx;
    const float* bsrc = (kb < 16) ? Wi : Wp;
    const int k0 = (kb & 15) * 32;
    __syncthreads();
#pragma unroll
    for (int c = 0; c < 2; ++c) {
      int s = c * 256 + tid;
      int row = s >> 2, sub = s & 3;
      const float* ap = asrc + (size_t)(m0 + row) * 512 + k0 + sub * 8;
      const float* bp = bsrc + (size_t)(n0 + row) * 512 + k0 + sub * 8;
      float4 a0 = *(const float4*)ap, a1 = *(const float4*)(ap + 4);
      float4 b0 = *(const float4*)bp, b1 = *(const float4*)(bp + 4);
      short8 av, bv;
      av[0] = (short)f2bf(a0.x); av[1] = (short)f2bf(a0.y);
      av[2] = (short)f2bf(a0.z); av[3] = (short)f2bf(a0.w);
      av[4] = (short)f2bf(a1.x); av[5] = (short)f2bf(a1.y);
      av[6] = (short)f2bf(a1.z); av[7] = (short)f2bf(a1.w);
      bv[0] = (short)f2bf(b0.x); bv[1] = (short)f2bf(b0.y);
      bv[2] = (short)f2bf(b0.z); bv[3] = (short)f2bf(b0.w);
      bv[4] = (short)f2bf(b1.x); bv[5] = (short)f2bf(b1.y);
      bv[6] = (short)f2bf(b1.z); bv[7] = (short)f2bf(b1.w);
      a_sm[row * 4 + sub] = av;
      b_sm[row * 4 + sub] = bv;
    }
    __syncthreads();
    short8 af[4], bf[4];
#pragma unroll
    for (int i = 0; i < 4; ++i) af[i] = a_sm[(wm + i * 16 + lm) * 4 + lq];
#pragma unroll
    for (int j = 0; j < 4; ++j) bf[j] = b_sm[(wn + j * 16 + lm) * 4 + lq];
#pragma unroll
    for (int i = 0; i < 4; ++i)
#pragma unroll
      for (int j = 0; j < 4; ++j)
        acc[i][j] = __builtin_amdgcn_mfma_f32_16x16x32_bf16(af[i], bf[j], acc[i][j], 0, 0, 0);
  }

#pragma unroll
  for (int j = 0; j < 4; ++j) {
    int n = n0 + wn + j * 16 + lm;
    float bias = args.bi[gate][n] + args.bh[gate][n] + args.bp[gate][n];
#pragma unroll
    for (int i = 0; i < 4; ++i) {
      int mbase = m0 + wm + i * 16 + lq * 4;
#pragma unroll
      for (int r = 0; r < 4; ++r) {
        int m = mbase + r;
        int t = m & 511, b = m >> 9;
        args.G[(size_t)gate * TBH + (size_t)(t * 64 + b) * 512 + n] = f2bf(acc[i][j][r] + bias);
      }
    }
  }
}

// -------------------------------------------------------------------------
// Recurrence: 128 persistent WGs = 4 batch-groups (16 batches, full MFMA
// rows) x 32 col-blocks (16 cols). Tagged self-synchronizing exchange:
// word = bf16(value)<<16 | tag;  h_t tag = 2t, rh_t/i_t tag = 2t+1.
// No flags, no vmcnt drains for ordering, no extra load trip after detect.
// h f32 is register-carried by owner lanes; only bf16 copy is exchanged.
// -------------------------------------------------------------------------
__global__ __launch_bounds__(256, 1) void recur_kernel(
    const unsigned short* __restrict__ G,
    const unsigned short* __restrict__ Whb,   // [3][512][512] bf16
    const float* __restrict__ h0,
    unsigned int* __restrict__ hpub,          // [64][512] tagged
    unsigned int* __restrict__ rhpub,         // [64][512] tagged
    unsigned int* __restrict__ ipub,          // [64][512] tagged (same-WG only)
    float* __restrict__ ys,                   // [64][512][512] f32
    float* __restrict__ hT) {                 // [64][512] f32
  __shared__ short8 w_sm[3 * 1024];  // [gate][kb][lane] frag-packed: 48 KB
  __shared__ short8 hp_sm[1024];     // h (phase A) then r*h (phase B): 16 KB

  const int tid = threadIdx.x;
  const int g = blockIdx.x >> 5;   // batch group 0..3
  const int cb = blockIdx.x & 31;  // col block 0..31
  const int b0 = g * 16;
  const int c0 = cb * 16;
  const int wave = tid >> 6, lane = tid & 63;
  const int lm = lane & 15, lq = lane >> 4;

  // ---- weight slices, fragment-packed (same layout as before) ----
#pragma unroll
  for (int gate = 0; gate < 3; ++gate) {
    for (int s = tid; s < 1024; s += 256) {
      int l = s & 63;
      w_sm[gate * 1024 + s] = *(const short8*)(Whb + (size_t)gate * 262144 +
          (size_t)(c0 + (l & 15)) * 512 + (s >> 6) * 32 + (l >> 4) * 8);
    }
  }

  // staging job offsets: job q covers hp_sm[s], s = tid + 256q
  unsigned int sb[4];
#pragma unroll
  for (int q = 0; q < 4; ++q) {
    int s = tid + 256 * q;
    sb[q] = (unsigned int)((b0 + (s & 15)) * 512 + (s >> 6) * 32 + ((s >> 4) & 3) * 8);
  }

  // per-lane (batch,col) ownership for waves 0/1 epilogues + publishes
  unsigned int pub[4];
  float hreg[4];  // f32 h carried in registers across steps (wave0)
  if (wave < 2) {
#pragma unroll
    for (int r = 0; r < 4; ++r) {
      pub[r] = (unsigned int)((b0 + lq * 4 + r) * 512 + c0 + lm);
      hreg[r] = h0[pub[r]];
    }
  }
  __syncthreads();

  unsigned int hyw[4];  // pending h publish words (wave0)

  for (int t = 0; t < 512; ++t) {
    const unsigned int tagA = 2u * (unsigned int)t;       // h_t
    const unsigned int tagB = 2u * (unsigned int)t + 1u;  // rh_t / i_t
    const unsigned int tagH = 2u * (unsigned int)t + 2u;  // h_{t+1}

    // ---- publish h_t (from prev step's regs) BEFORE polling for it ----
    if (wave == 0 && t > 0) {
#pragma unroll
      for (int r = 0; r < 4; ++r) dev_store(hpub + pub[r], hyw[r]);
    }
    // ---- G prefetch (HBM latency hides under the poll) ----
    float gv[4], gvB[4];
    if (wave < 2) {
      const unsigned short* Gp = G + (size_t)wave * TBH + (size_t)t * 32768;
#pragma unroll
      for (int r = 0; r < 4; ++r) gv[r] = bfbits2f(Gp[pub[r]]);
      if (wave == 0) {
        const unsigned short* Gn = G + 2 * TBH + (size_t)t * 32768;
#pragma unroll
        for (int r = 0; r < 4; ++r) gvB[r] = bfbits2f(Gn[pub[r]]);
      }
    }

    // ---- stage h: poll tagged words until all carry tagA ----
    {
      unsigned int v[4][8];
#pragma unroll
      for (int q = 0; q < 4; ++q)
#pragma unroll
        for (int j = 0; j < 8; ++j) v[q][j] = dev_load(hpub + sb[q] + j);
      for (;;) {
        bool ok = true;
#pragma unroll
        for (int q = 0; q < 4; ++q)
#pragma unroll
          for (int j = 0; j < 8; ++j) ok &= ((v[q][j] & 0xffffu) == tagA);
        if (ok) break;
#pragma unroll
        for (int q = 0; q < 4; ++q) {
          bool stale = false;
#pragma unroll
          for (int j = 0; j < 8; ++j) stale |= ((v[q][j] & 0xffffu) != tagA);
          if (stale) {
#pragma unroll
            for (int j = 0; j < 8; ++j) v[q][j] = dev_load(hpub + sb[q] + j);
          }
        }
      }
#pragma unroll
      for (int q = 0; q < 4; ++q) {
        short8 pv;
#pragma unroll
        for (int j = 0; j < 8; ++j) pv[j] = (short)(v[q][j] >> 16);
        hp_sm[tid + 256 * q] = pv;
      }
    }
    __syncthreads();

    // ---- phase A: wave0 -> r gate, wave1 -> i gate ----
    unsigned int abw[4];
    if (wave < 2) {
      floatx4 acc = {0.f, 0.f, 0.f, 0.f};
#pragma unroll
      for (int kb = 0; kb < 16; ++kb)
        acc = __builtin_amdgcn_mfma_f32_16x16x32_bf16(
            hp_sm[kb * 64 + lane], w_sm[wave * 1024 + kb * 64 + lane], acc, 0, 0, 0);
#pragma unroll
      for (int r = 0; r < 4; ++r) {
        float sv = 1.f / (1.f + __expf(-(acc[r] + gv[r])));
        float outv = (wave == 0) ? sv * hreg[r] : sv;
        abw[r] = (((unsigned int)f2bf(outv)) << 16) | tagB;
      }
    }
    __syncthreads();  // all hp_sm (h) reads done

    // ---- publish rh / i, then stage r*h with tagB poll ----
    if (wave < 2) {
      unsigned int* dst = (wave == 0) ? rhpub : ipub;
#pragma unroll
      for (int r = 0; r < 4; ++r) dev_store(dst + pub[r], abw[r]);
    }
    {
      unsigned int v[4][8];
#pragma unroll
      for (int q = 0; q < 4; ++q)
#pragma unroll
        for (int j = 0; j < 8; ++j) v[q][j] = dev_load(rhpub + sb[q] + j);
      for (;;) {
        bool ok = true;
#pragma unroll
        for (int q = 0; q < 4; ++q)
#pragma unroll
          for (int j = 0; j < 8; ++j) ok &= ((v[q][j] & 0xffffu) == tagB);
        if (ok) break;
#pragma unroll
        for (int q = 0; q < 4; ++q) {
          bool stale = false;
#pragma unroll
          for (int j = 0; j < 8; ++j) stale |= ((v[q][j] & 0xffffu) != tagB);
          if (stale) {
#pragma unroll
            for (int j = 0; j < 8; ++j) v[q][j] = dev_load(rhpub + sb[q] + j);
          }
        }
      }
#pragma unroll
      for (int q = 0; q < 4; ++q) {
        short8 pv;
#pragma unroll
        for (int j = 0; j < 8; ++j) pv[j] = (short)(v[q][j] >> 16);
        hp_sm[tid + 256 * q] = pv;
      }
    }
    __syncthreads();

    // ---- phase B: wave0 -> n gate + h update ----
    if (wave == 0) {
      unsigned int ivw[4];
#pragma unroll
      for (int r = 0; r < 4; ++r) ivw[r] = dev_load(ipub + pub[r]);
      for (;;) {
        bool ok = true;
#pragma unroll
        for (int r = 0; r < 4; ++r) ok &= ((ivw[r] & 0xffffu) == tagB);
        if (ok) break;
#pragma unroll
        for (int r = 0; r < 4; ++r)
          if ((ivw[r] & 0xffffu) != tagB) ivw[r] = dev_load(ipub + pub[r]);
      }
      floatx4 acc = {0.f, 0.f, 0.f, 0.f};
#pragma unroll
      for (int kb = 0; kb < 16; ++kb)
        acc = __builtin_amdgcn_mfma_f32_16x16x32_bf16(
            hp_sm[kb * 64 + lane], w_sm[2 * 1024 + kb * 64 + lane], acc, 0, 0, 0);
#pragma unroll
      for (int r = 0; r < 4; ++r) {
        float ivf = bfbits2f((unsigned short)(ivw[r] >> 16));
        float pre = acc[r] + gvB[r];
        float e = __expf(2.f * pre);
        float nv = 1.f - 2.f / (e + 1.f);  // tanh
        float hy = (1.f - ivf) * hreg[r] + ivf * nv;
        hreg[r] = hy;
        hyw[r] = (((unsigned int)f2bf(hy)) << 16) | tagH;
        ys[(size_t)(b0 + lq * 4 + r) * 262144 + (size_t)t * 512 + (c0 + lm)] = hy;
      }
      if (t == 511) {
#pragma unroll
        for (int r = 0; r < 4; ++r) hT[pub[r]] = hreg[r];
      }
    }
    __syncthreads();  // guard hp_sm before next step's restage
  }
}

// -------------------------------------------------------------------------
extern "C" void kernel_launch(void* const* d_in, const int* in_sizes, int n_in,
                              void* d_out, int out_size, void* d_ws, size_t ws_size,
                              hipStream_t stream) {
  typedef const float* cfp;
  cfp x = (cfp)d_in[0];
  cfp h0 = (cfp)d_in[1];
  cfp ctx = (cfp)d_in[2];

  PreArgs pa;
  pa.x = x;
  pa.ctx = ctx;
  for (int gi = 0; gi < 3; ++gi) {
    pa.Wi[gi] = (cfp)d_in[3 + 6 * gi];
    pa.bi[gi] = (cfp)d_in[4 + 6 * gi];
    pa.bh[gi] = (cfp)d_in[6 + 6 * gi];
    pa.Wp[gi] = (cfp)d_in[7 + 6 * gi];
    pa.bp[gi] = (cfp)d_in[8 + 6 * gi];
  }
  cfp Whr = (cfp)d_in[5], Whi = (cfp)d_in[11], Whn = (cfp)d_in[17];

  char* ws = (char*)d_ws;
  unsigned short* G = (unsigned short*)ws;          // 3 gates x 32 MB bf16
  size_t off = (size_t)3 * TBH * 2;                 // 100,663,296 B
  unsigned short* Whb = (unsigned short*)(ws + off);
  off += (size_t)3 * 262144 * 2;                    // 1,572,864 B
  unsigned int* hpub = (unsigned int*)(ws + off);
  off += (size_t)64 * 512 * 4;
  unsigned int* rhpub = (unsigned int*)(ws + off);
  off += (size_t)64 * 512 * 4;
  unsigned int* ipub = (unsigned int*)(ws + off);
  off += (size_t)64 * 512 * 4;
  pa.G = G;

  float* out = (float*)d_out;
  float* ys = out;
  float* hT = out + (size_t)64 * 512 * 512;

  prep_kernel<<<1024, 256, 0, stream>>>(h0, hpub, rhpub, ipub, Whr, Whi, Whn, Whb);
  dim3 gp(4, 256, 3);
  gemm_pre<<<gp, 256, 0, stream>>>(pa);
  recur_kernel<<<128, 256, 0, stream>>>(G, Whb, h0, hpub, rhpub, ipub, ys, hT);
}

// Round 2
// 4173.401 us; speedup vs baseline: 1.5760x; 1.5760x over previous
//
#include <hip/hip_runtime.h>
#include <hip/hip_bf16.h>

// Inputs/outputs are FLOAT32 (per reference). Compute uses bf16 MFMA.
typedef __attribute__((ext_vector_type(8))) short short8;   // 8 bf16 = 4 VGPRs (MFMA A/B frag)
typedef __attribute__((ext_vector_type(4))) float floatx4;  // MFMA C/D frag

#define TBH ((size_t)16777216)  // 32768*512 per-gate G stride (elements)

__device__ __forceinline__ float bfbits2f(unsigned short b) {
  return __uint_as_float(((unsigned int)b) << 16);
}
__device__ __forceinline__ unsigned short f2bf(float f) {
  unsigned int u = __float_as_uint(f);
  unsigned int r = (u + 0x7fffu + ((u >> 16) & 1u)) >> 16;  // RNE
  return (unsigned short)r;
}

// Relaxed device-scope atomics (bypass non-coherent per-XCD caches). Every
// exchanged 4B word is self-contained: bf16 value in high 16 | step tag low 16.
__device__ __forceinline__ void dev_store(unsigned int* p, unsigned int v) {
  __hip_atomic_store(p, v, __ATOMIC_RELAXED, __HIP_MEMORY_SCOPE_AGENT);
}
__device__ __forceinline__ unsigned int dev_load(const unsigned int* p) {
  return __hip_atomic_load(p, __ATOMIC_RELAXED, __HIP_MEMORY_SCOPE_AGENT);
}

// LDS barrier WITHOUT vmcnt(0) drain: publish stores stay in flight across
// the barrier (their ack overlaps the next poll). lgkmcnt(0) orders LDS.
// sched_barrier(0) per guide rule #18 (prevent hoisting past the asm wait).
#define LBAR()                                              \
  do {                                                      \
    asm volatile("s_waitcnt lgkmcnt(0)" ::: "memory");      \
    __builtin_amdgcn_s_barrier();                           \
    __builtin_amdgcn_sched_barrier(0);                      \
  } while (0)

// -------------------------------------------------------------------------
// prep: hpub[i] = bf16(h0)<<16 | tag0 ; rhpub = 0 ; Whr/Whi/Whn -> bf16.
// -------------------------------------------------------------------------
__global__ void prep_kernel(const float* __restrict__ h0,
                            unsigned int* __restrict__ hpub,
                            unsigned int* __restrict__ rhpub,
                            const float* __restrict__ Whr,
                            const float* __restrict__ Whi,
                            const float* __restrict__ Whn,
                            unsigned short* __restrict__ Whb) {
  int i = blockIdx.x * 256 + threadIdx.x;  // grid 1024*256 = 262144
  if (i < 64 * 512) {
    hpub[i] = ((unsigned int)f2bf(h0[i])) << 16;  // tag 0 == h_0 tag
    rhpub[i] = 0u;                                // != first rh tag (1)
  }
#pragma unroll
  for (int rep = 0; rep < 3; ++rep) {
    int j = i + rep * 262144;
    float v = (j < 262144) ? Whr[j] : ((j < 524288) ? Whi[j - 262144] : Whn[j - 524288]);
    Whb[j] = f2bf(v);
  }
}

// -------------------------------------------------------------------------
// Phase 1: G[gate][t*64+b][n] = x@Wi^T + ctx@Wp^T + (bi+bh+bp)   (bf16 out)
// (unchanged)
// -------------------------------------------------------------------------
struct PreArgs {
  const float* x;
  const float* ctx;
  const float* Wi[3];
  const float* Wp[3];
  const float* bi[3];
  const float* bh[3];
  const float* bp[3];
  unsigned short* G;
};

__global__ __launch_bounds__(256) void gemm_pre(PreArgs args) {
  __shared__ short8 a_sm[512];  // [row(128)][sub(4)] : 128x32 bf16
  __shared__ short8 b_sm[512];
  const int tid = threadIdx.x;
  const int gate = blockIdx.z;
  const int n0 = blockIdx.x * 128;
  const int m0 = blockIdx.y * 128;
  const int wave = tid >> 6, lane = tid & 63;
  const int wm = (wave & 1) * 64, wn = (wave >> 1) * 64;
  const int lm = lane & 15, lq = lane >> 4;
  const float* Wi = args.Wi[gate];
  const float* Wp = args.Wp[gate];

  floatx4 acc[4][4];
#pragma unroll
  for (int i = 0; i < 4; ++i)
#pragma unroll
    for (int j = 0; j < 4; ++j) acc[i][j] = floatx4{0.f, 0.f, 0.f, 0.f};

  for (int kb = 0; kb < 32; ++kb) {
    const float* asrc = (kb < 16) ? args.x : args.ctx;
    const float* bsrc = (kb < 16) ? Wi : Wp;
    const int k0 = (kb & 15) * 32;
    __syncthreads();
#pragma unroll
    for (int c = 0; c < 2; ++c) {
      int s = c * 256 + tid;
      int row = s >> 2, sub = s & 3;
      const float* ap = asrc + (size_t)(m0 + row) * 512 + k0 + sub * 8;
      const float* bp = bsrc + (size_t)(n0 + row) * 512 + k0 + sub * 8;
      float4 a0 = *(const float4*)ap, a1 = *(const float4*)(ap + 4);
      float4 b0 = *(const float4*)bp, b1 = *(const float4*)(bp + 4);
      short8 av, bv;
      av[0] = (short)f2bf(a0.x); av[1] = (short)f2bf(a0.y);
      av[2] = (short)f2bf(a0.z); av[3] = (short)f2bf(a0.w);
      av[4] = (short)f2bf(a1.x); av[5] = (short)f2bf(a1.y);
      av[6] = (short)f2bf(a1.z); av[7] = (short)f2bf(a1.w);
      bv[0] = (short)f2bf(b0.x); bv[1] = (short)f2bf(b0.y);
      bv[2] = (short)f2bf(b0.z); bv[3] = (short)f2bf(b0.w);
      bv[4] = (short)f2bf(b1.x); bv[5] = (short)f2bf(b1.y);
      bv[6] = (short)f2bf(b1.z); bv[7] = (short)f2bf(b1.w);
      a_sm[row * 4 + sub] = av;
      b_sm[row * 4 + sub] = bv;
    }
    __syncthreads();
    short8 af[4], bf[4];
#pragma unroll
    for (int i = 0; i < 4; ++i) af[i] = a_sm[(wm + i * 16 + lm) * 4 + lq];
#pragma unroll
    for (int j = 0; j < 4; ++j) bf[j] = b_sm[(wn + j * 16 + lm) * 4 + lq];
#pragma unroll
    for (int i = 0; i < 4; ++i)
#pragma unroll
      for (int j = 0; j < 4; ++j)
        acc[i][j] = __builtin_amdgcn_mfma_f32_16x16x32_bf16(af[i], bf[j], acc[i][j], 0, 0, 0);
  }

#pragma unroll
  for (int j = 0; j < 4; ++j) {
    int n = n0 + wn + j * 16 + lm;
    float bias = args.bi[gate][n] + args.bh[gate][n] + args.bp[gate][n];
#pragma unroll
    for (int i = 0; i < 4; ++i) {
      int mbase = m0 + wm + i * 16 + lq * 4;
#pragma unroll
      for (int r = 0; r < 4; ++r) {
        int m = mbase + r;
        int t = m & 511, b = m >> 9;
        args.G[(size_t)gate * TBH + (size_t)(t * 64 + b) * 512 + n] = f2bf(acc[i][j][r] + bias);
      }
    }
  }
}

// -------------------------------------------------------------------------
// Recurrence: 16 WGs = 4 batch-groups (16 batches) x 4 col-slices (128 cols).
// 512 threads = 8 waves; wave w owns 16-col chunk cw0 for ALL 3 gates.
// Weights live in VGPRs (48 short8/lane). h,i carried in owner-lane regs.
// Per step: 2 tagged exchanges (h, r*h), fan-in 4, local slice via LDS.
// One 16KB frag buffer reused h -> rh -> h (disjoint kb regions at any time).
// -------------------------------------------------------------------------
__global__ __launch_bounds__(512, 2) void recur_kernel(
    const unsigned short* __restrict__ G,
    const unsigned short* __restrict__ Whb,   // [3][512][512] bf16
    const float* __restrict__ h0,
    unsigned int* __restrict__ hpub,          // [64][512] bf16<<16 | tag(t)
    unsigned int* __restrict__ rhpub,         // [64][512] bf16<<16 | tag(t+1)
    float* __restrict__ ys,                   // [64][512][512] f32
    float* __restrict__ hT) {                 // [64][512] f32
  __shared__ short8 fragbuf[1024];  // [kb(16)][lane'(64)] A-frags: 16 KB

  const int tid = threadIdx.x;
  const int g = blockIdx.x >> 2;   // batch group 0..3
  const int cb = blockIdx.x & 3;   // col slice 0..3 (128 cols)
  const int b0 = g * 16;
  const int c0 = cb * 128;
  const int wave = tid >> 6, lane = tid & 63;
  const int lm = lane & 15, lq = lane >> 4;
  const int cw0 = c0 + wave * 16;  // wave's 16-col chunk (== global k index)
  const int prow = lq * 4;         // lane's 4 rows prow..prow+3

  // ---- weights -> registers (static indices only; addresses runtime) ----
  short8 wrl[4], wil[4], wnl[4];    // local slice kb = cb*4+q
  short8 wrr[12], wir[12], wnr[12]; // remote: j -> rcb=(cb+1+(j>>2))&3, kb=rcb*4+(j&3)
  {
    const unsigned short* Wb = Whb + (size_t)(cw0 + lm) * 512 + lq * 8;
#pragma unroll
    for (int q = 0; q < 4; ++q) {
      const int kb = cb * 4 + q;
      wrl[q] = *(const short8*)(Wb + 0 * 262144 + kb * 32);
      wil[q] = *(const short8*)(Wb + 1 * 262144 + kb * 32);
      wnl[q] = *(const short8*)(Wb + 2 * 262144 + kb * 32);
    }
#pragma unroll
    for (int j = 0; j < 12; ++j) {
      const int kb = (((cb + 1 + (j >> 2)) & 3) << 2) + (j & 3);
      wrr[j] = *(const short8*)(Wb + 0 * 262144 + kb * 32);
      wir[j] = *(const short8*)(Wb + 1 * 262144 + kb * 32);
      wnr[j] = *(const short8*)(Wb + 2 * 262144 + kb * 32);
    }
  }

  // ---- staging map: thread covers (srow, skk..skk+3) of a 16x128 slice ----
  const int srow = tid >> 5;          // 0..15
  const int skk = (tid * 4) & 127;    // 0,4,...,124 (4-aligned, never crosses 8)
  const int sl = srow + 16 * ((skk >> 3) & 3);                  // lane'
  const int su2 = ((skk >> 5) * 64 + sl) * 2 + ((skk >> 2) & 1);  // uint2 idx within slice
  uint2* f2 = (uint2*)fragbuf;
  unsigned short* fus = (unsigned short*)fragbuf;

  // ---- epilogue LDS write position for lane's column k = cw0+lm ----
  const int kcol = cw0 + lm;
  const int eidx = ((kcol >> 5) * 64 + 16 * ((kcol >> 3) & 3)) * 8 + (kcol & 7);  // + row*8

  // ---- h0: registers + local slice of fragbuf ----
  float hreg[4], ireg[4];
#pragma unroll
  for (int r = 0; r < 4; ++r) hreg[r] = h0[(size_t)(b0 + prow + r) * 512 + kcol];
  {
    const float* hp = h0 + (size_t)(b0 + srow) * 512 + c0 + skk;
    float4 v = *(const float4*)hp;
    uint2 p;
    p.x = (unsigned int)f2bf(v.x) | ((unsigned int)f2bf(v.y) << 16);
    p.y = (unsigned int)f2bf(v.z) | ((unsigned int)f2bf(v.w) << 16);
    f2[su2 + cb * 512] = p;
  }
  __syncthreads();

  for (int t = 0; t < 512; ++t) {
    const unsigned int tgh = (unsigned int)t;        // tag of h_t
    const unsigned int tgr = (unsigned int)(t + 1);  // tag of rh_t / i_t / h_{t+1}

    // ---- G prefetch for r,i ----
    float gr[4], gi[4];
    const unsigned short* Gt = G + ((size_t)(t * 64 + b0 + prow)) * 512 + kcol;
#pragma unroll
    for (int r = 0; r < 4; ++r) {
      gr[r] = bfbits2f(Gt[r * 512]);
      gi[r] = bfbits2f(Gt[TBH + r * 512]);
    }

    floatx4 ar = {0.f, 0.f, 0.f, 0.f}, ai = {0.f, 0.f, 0.f, 0.f};
    {
      // ---- issue remote-h poll loads ----
      unsigned int v[12];
      unsigned int* hb = hpub + (unsigned)(b0 + srow) * 512;
#pragma unroll
      for (int s = 0; s < 3; ++s) {
        const int off = (((cb + 1 + s) & 3) << 7) + skk;
#pragma unroll
        for (int j = 0; j < 4; ++j) v[s * 4 + j] = dev_load(hb + off + j);
      }
      // ---- local MFMAs while loads fly ----
#pragma unroll
      for (int q = 0; q < 4; ++q) {
        short8 hf = fragbuf[(cb * 4 + q) * 64 + lane];
        ar = __builtin_amdgcn_mfma_f32_16x16x32_bf16(hf, wrl[q], ar, 0, 0, 0);
        ai = __builtin_amdgcn_mfma_f32_16x16x32_bf16(hf, wil[q], ai, 0, 0, 0);
      }
      // ---- poll (per-slice retry) ----
      for (;;) {
        bool ok = true;
#pragma unroll
        for (int i = 0; i < 12; ++i) ok &= ((v[i] & 0xffffu) == tgh);
        if (ok) break;
#pragma unroll
        for (int s = 0; s < 3; ++s) {
          bool st = false;
#pragma unroll
          for (int j = 0; j < 4; ++j) st |= ((v[s * 4 + j] & 0xffffu) != tgh);
          if (st) {
            const int off = (((cb + 1 + s) & 3) << 7) + skk;
#pragma unroll
            for (int j = 0; j < 4; ++j) v[s * 4 + j] = dev_load(hb + off + j);
          }
        }
      }
      // ---- stage remote slices ----
#pragma unroll
      for (int s = 0; s < 3; ++s) {
        const int rcb = (cb + 1 + s) & 3;
        uint2 p;
        p.x = (v[s * 4 + 0] >> 16) | (v[s * 4 + 1] & 0xffff0000u);
        p.y = (v[s * 4 + 2] >> 16) | (v[s * 4 + 3] & 0xffff0000u);
        f2[su2 + rcb * 512] = p;
      }
    }
    LBAR();  // remote h staged

    // ---- remote MFMAs (r,i) ----
#pragma unroll
    for (int j = 0; j < 12; ++j) {
      const int kb = (((cb + 1 + (j >> 2)) & 3) << 2) + (j & 3);
      short8 hf = fragbuf[kb * 64 + lane];
      ar = __builtin_amdgcn_mfma_f32_16x16x32_bf16(hf, wrr[j], ar, 0, 0, 0);
      ai = __builtin_amdgcn_mfma_f32_16x16x32_bf16(hf, wir[j], ai, 0, 0, 0);
    }

    // ---- epilogue A: sigmoid, publish rh, local rh -> fragbuf ----
    {
      unsigned int* rb = rhpub + (unsigned)(b0 + prow) * 512 + kcol;
#pragma unroll
      for (int r = 0; r < 4; ++r) {
        float sv = 1.f / (1.f + __expf(-(ar[r] + gr[r])));
        float rh = sv * hreg[r];
        ireg[r] = 1.f / (1.f + __expf(-(ai[r] + gi[r])));
        unsigned short rbits = f2bf(rh);
        dev_store(rb + r * 512, (((unsigned int)rbits) << 16) | tgr);
        fus[eidx + (prow + r) * 8] = rbits;
      }
    }
    LBAR();  // local rh visible in fragbuf

    // ---- G prefetch for n ----
    float gn[4];
#pragma unroll
    for (int r = 0; r < 4; ++r) gn[r] = bfbits2f(Gt[2 * TBH + r * 512]);

    floatx4 an = {0.f, 0.f, 0.f, 0.f};
    {
      // ---- issue remote-rh poll loads ----
      unsigned int v[12];
      unsigned int* rbb = rhpub + (unsigned)(b0 + srow) * 512;
#pragma unroll
      for (int s = 0; s < 3; ++s) {
        const int off = (((cb + 1 + s) & 3) << 7) + skk;
#pragma unroll
        for (int j = 0; j < 4; ++j) v[s * 4 + j] = dev_load(rbb + off + j);
      }
      // ---- local MFMAs (n) ----
#pragma unroll
      for (int q = 0; q < 4; ++q) {
        short8 hf = fragbuf[(cb * 4 + q) * 64 + lane];
        an = __builtin_amdgcn_mfma_f32_16x16x32_bf16(hf, wnl[q], an, 0, 0, 0);
      }
      // ---- poll ----
      for (;;) {
        bool ok = true;
#pragma unroll
        for (int i = 0; i < 12; ++i) ok &= ((v[i] & 0xffffu) == tgr);
        if (ok) break;
#pragma unroll
        for (int s = 0; s < 3; ++s) {
          bool st = false;
#pragma unroll
          for (int j = 0; j < 4; ++j) st |= ((v[s * 4 + j] & 0xffffu) != tgr);
          if (st) {
            const int off = (((cb + 1 + s) & 3) << 7) + skk;
#pragma unroll
            for (int j = 0; j < 4; ++j) v[s * 4 + j] = dev_load(rbb + off + j);
          }
        }
      }
      // ---- stage remote rh ----
#pragma unroll
      for (int s = 0; s < 3; ++s) {
        const int rcb = (cb + 1 + s) & 3;
        uint2 p;
        p.x = (v[s * 4 + 0] >> 16) | (v[s * 4 + 1] & 0xffff0000u);
        p.y = (v[s * 4 + 2] >> 16) | (v[s * 4 + 3] & 0xffff0000u);
        f2[su2 + rcb * 512] = p;
      }
    }
    LBAR();  // remote rh staged

    // ---- remote MFMAs (n) ----
#pragma unroll
    for (int j = 0; j < 12; ++j) {
      const int kb = (((cb + 1 + (j >> 2)) & 3) << 2) + (j & 3);
      short8 hf = fragbuf[kb * 64 + lane];
      an = __builtin_amdgcn_mfma_f32_16x16x32_bf16(hf, wnr[j], an, 0, 0, 0);
    }

    // ---- epilogue B: tanh, blend, ys, publish h, local h -> fragbuf ----
    {
      unsigned int* hb = hpub + (unsigned)(b0 + prow) * 512 + kcol;
      float* yp = ys + (size_t)(b0 + prow) * 262144 + (size_t)t * 512 + kcol;
#pragma unroll
      for (int r = 0; r < 4; ++r) {
        float pre = an[r] + gn[r];
        float e = __expf(2.f * pre);
        float nv = 1.f - 2.f / (e + 1.f);  // tanh
        float hy = (1.f - ireg[r]) * hreg[r] + ireg[r] * nv;
        hreg[r] = hy;
        unsigned short hbits = f2bf(hy);
        dev_store(hb + r * 512, (((unsigned int)hbits) << 16) | tgr);
        yp[(size_t)r * 262144] = hy;
        fus[eidx + (prow + r) * 8] = hbits;
      }
      if (t == 511) {
#pragma unroll
        for (int r = 0; r < 4; ++r) hT[(size_t)(b0 + prow + r) * 512 + kcol] = hreg[r];
      }
    }
    LBAR();  // local h_{t+1} visible for next step's local MFMAs
  }
}

// -------------------------------------------------------------------------
extern "C" void kernel_launch(void* const* d_in, const int* in_sizes, int n_in,
                              void* d_out, int out_size, void* d_ws, size_t ws_size,
                              hipStream_t stream) {
  typedef const float* cfp;
  cfp x = (cfp)d_in[0];
  cfp h0 = (cfp)d_in[1];
  cfp ctx = (cfp)d_in[2];

  PreArgs pa;
  pa.x = x;
  pa.ctx = ctx;
  for (int gi = 0; gi < 3; ++gi) {
    pa.Wi[gi] = (cfp)d_in[3 + 6 * gi];
    pa.bi[gi] = (cfp)d_in[4 + 6 * gi];
    pa.bh[gi] = (cfp)d_in[6 + 6 * gi];
    pa.Wp[gi] = (cfp)d_in[7 + 6 * gi];
    pa.bp[gi] = (cfp)d_in[8 + 6 * gi];
  }
  cfp Whr = (cfp)d_in[5], Whi = (cfp)d_in[11], Whn = (cfp)d_in[17];

  char* ws = (char*)d_ws;
  unsigned short* G = (unsigned short*)ws;          // 3 gates x 32 MB bf16
  size_t off = (size_t)3 * TBH * 2;                 // 100,663,296 B
  unsigned short* Whb = (unsigned short*)(ws + off);
  off += (size_t)3 * 262144 * 2;                    // 1,572,864 B
  unsigned int* hpub = (unsigned int*)(ws + off);
  off += (size_t)64 * 512 * 4;
  unsigned int* rhpub = (unsigned int*)(ws + off);
  off += (size_t)64 * 512 * 4;
  pa.G = G;

  float* out = (float*)d_out;
  float* ys = out;
  float* hT = out + (size_t)64 * 512 * 512;

  prep_kernel<<<1024, 256, 0, stream>>>(h0, hpub, rhpub, Whr, Whi, Whn, Whb);
  dim3 gp(4, 256, 3);
  gemm_pre<<<gp, 256, 0, stream>>>(pa);
  recur_kernel<<<16, 512, 0, stream>>>(G, Whb, h0, hpub, rhpub, ys, hT);
}